// Round 1
// 284.446 us; speedup vs baseline: 1.0666x; 1.0666x over previous
//
#include <hip/hip_runtime.h>

// ---- problem constants ----
#define BSZ 4
#define SEQ 2048
#define DIM 1024
#define NH  16
#define HD  64
#define QT  128   // q rows per block pass (flash)
#define KT  64    // kv rows per tile (flash)
#define PAD 72    // u16 row stride in flash LDS
#define NKT (DIM / 64)  // 16 K-tiles of 64 for the 256^2 GEMM

typedef float v4f __attribute__((ext_vector_type(4)));
typedef short s8v __attribute__((ext_vector_type(8)));
typedef unsigned short u16;
typedef unsigned short u16x8 __attribute__((ext_vector_type(8)));
typedef unsigned short u16x4 __attribute__((ext_vector_type(4)));
typedef unsigned int u32;

__device__ __forceinline__ u16 f2bf(float f) {
  u32 u = __builtin_bit_cast(u32, f);
  u32 r = u + 0x7fffu + ((u >> 16) & 1u);  // RNE
  return (u16)(r >> 16);
}
__device__ __forceinline__ float bf2f(u16 h) {
  return __builtin_bit_cast(float, (u32)h << 16);
}
__device__ __forceinline__ float fast_exp2(float x) {
#if __has_builtin(__builtin_amdgcn_exp2f)
  return __builtin_amdgcn_exp2f(x);
#else
  return exp2f(x);
#endif
}
// async global->LDS, 16B per lane; lds ptr must be wave-uniform (HW adds lane*16)
__device__ __forceinline__ void gll16(const u16* g, u16* l) {
  __builtin_amdgcn_global_load_lds((const __attribute__((address_space(1))) void*)g,
                                   (__attribute__((address_space(3))) void*)l, 16, 0, 0);
}
// raw s_barrier via inline asm: SIInsertWaitcnts does NOT recognize it, so no
// forced vmcnt(0) drain (unlike __syncthreads / S_BARRIER opcode). "memory"
// clobber stops the compiler from moving LDS/global ops across it.
__device__ __forceinline__ void wg_barrier() { asm volatile("s_barrier" ::: "memory"); }
// s_waitcnt imm: vmcnt[3:0] | expcnt<<4 | lgkmcnt<<8 | vmcnt[5:4]<<14
#define WAITCNT_VM4   0xF74   // vmcnt(4), lgkm/exp unconstrained
#define WAITCNT_VM0   0xF70   // vmcnt(0)
#define WAITCNT_LGKM0 0xC07F  // lgkmcnt(0), vm/exp unconstrained

// ---------------- cast x (fp32) -> bf16 ----------------
__global__ __launch_bounds__(256) void cast_bf16_kernel(const float* __restrict__ x,
                                                        u16* __restrict__ o, int n4) {
  int i = blockIdx.x * 256 + threadIdx.x;
  if (i >= n4) return;
  v4f v = reinterpret_cast<const v4f*>(x)[i];
  u16x4 r;
  #pragma unroll
  for (int c = 0; c < 4; c++) r[c] = f2bf(v[c]);
  reinterpret_cast<u16x4*>(o)[i] = r;
}

// ---------------- transpose + cast W[k][n] -> Wt[n][k] bf16 ----------------
// z==0 (Wq) folds in the attention scale 1/sqrt(HD)*log2(e): Q leaves the QKV
// GEMM pre-scaled for the exp2-domain softmax (flash staging is a pure copy).
__global__ __launch_bounds__(256) void transpose_cast_kernel(const float* __restrict__ W0,
                                                             const float* __restrict__ W1,
                                                             const float* __restrict__ W2,
                                                             const float* __restrict__ W3,
                                                             u16* __restrict__ out) {
  const float* W = blockIdx.z == 0 ? W0 : blockIdx.z == 1 ? W1 : blockIdx.z == 2 ? W2 : W3;
  const float scale = (blockIdx.z == 0) ? 0.18033688011112042f : 1.0f;
  u16* T = out + (size_t)blockIdx.z * DIM * DIM;
  __shared__ float tile[32][33];
  int tx = threadIdx.x & 31, ty = threadIdx.x >> 5;
  int bn = blockIdx.x * 32, bk = blockIdx.y * 32;
  #pragma unroll
  for (int r = 0; r < 4; r++) {
    int k = bk + ty + r * 8;
    tile[ty + r * 8][tx] = W[(size_t)k * DIM + bn + tx];
  }
  __syncthreads();
  #pragma unroll
  for (int r = 0; r < 4; r++) {
    int n = bn + ty + r * 8;
    T[(size_t)n * DIM + bk + tx] = f2bf(tile[tx][ty + r * 8] * scale);
  }
}

// ======== 256x256 8-phase GEMM core (BK=64, 512 thr = 8 waves 2Mx4N) ========
// Schedule per the T3+T4 template: K-tile = 64 split into 4 phases of 16 MFMA
// (phase = (kc half, mh quadrant)). Each phase: 8x ds_read_b128 -> issue one
// 16KB staging unit (2 gll16/wave) -> raw barrier -> lgkmcnt(0) -> setprio(1)
// 16 MFMA setprio(0) -> barrier. One counted vmcnt(4) per K-tile boundary
// (2 units = 4 loads in flight), never 0 in the main loop.
//
// LDS (dynamic 128KB): A[2 dbuf][2 kc][16KB] at u16 0, B same at u16 32768.
// Unit layout (chunked, gll16 lane-linear => conflict-free ds_read, measured 0
// conflicts with this pattern): 16-row group j at j*1KB, within group chunk =
// kchunk*16 + (row&15). Frag read: lane reads row=l16, k=quad*8..+8 (16B).
//
// Staging lifetime proof: unit (t,kc=0) read at phases p0/p1 of tile t, free
// after p1's trailing barrier -> overwrite (t+2,kc0) issued at t.p2/p3; unit
// (t,kc=1) read p2/p3 -> overwrite (t+2,kc1) issued at (t+1).p0/p1. Boundary
// vmcnt(4) leaves only the 2 youngest units ((t+1,kc0) pair) outstanding, so
// every unit of tile t+1's first phases has landed.

#define ST_A(t_, kc_)                                                             \
  gll16(Ag0 + (t_) * 64 + (kc_) * 32, Aw0 + ((t_)&1) * 16384 + (kc_) * 8192);     \
  gll16(Ag1 + (t_) * 64 + (kc_) * 32, Aw1 + ((t_)&1) * 16384 + (kc_) * 8192);
#define ST_B(t_, kc_)                                                             \
  gll16(Bg0 + (t_) * 64 + (kc_) * 32, Bw0 + ((t_)&1) * 16384 + (kc_) * 8192);     \
  gll16(Bg1 + (t_) * 64 + (kc_) * 32, Bw1 + ((t_)&1) * 16384 + (kc_) * 8192);

#define PH(t_, kc_, mh_, STAGES, TAILW)                                           \
  { const u16* Ab = AL + ((t_)&1) * 16384 + (kc_) * 8192 + aRd;                   \
    const u16* Bb = BL + ((t_)&1) * 16384 + (kc_) * 8192 + bRd;                   \
    s8v af[4], bf[4];                                                             \
    _Pragma("unroll") for (int i_ = 0; i_ < 4; i_++)                              \
      af[i_] = *(const s8v*)(Ab + ((mh_) * 4 + i_) * 512);                        \
    _Pragma("unroll") for (int j_ = 0; j_ < 4; j_++)                              \
      bf[j_] = *(const s8v*)(Bb + j_ * 512);                                      \
    STAGES                                                                        \
    wg_barrier();                                                                 \
    __builtin_amdgcn_s_waitcnt(WAITCNT_LGKM0);                                    \
    __builtin_amdgcn_s_setprio(1);                                                \
    _Pragma("unroll") for (int i_ = 0; i_ < 4; i_++)                              \
      _Pragma("unroll") for (int j_ = 0; j_ < 4; j_++)                            \
        acc[(mh_) * 4 + i_][j_] = __builtin_amdgcn_mfma_f32_16x16x32_bf16(        \
            af[i_], bf[j_], acc[(mh_) * 4 + i_][j_], 0, 0, 0);                    \
    __builtin_amdgcn_s_setprio(0);                                                \
    TAILW                                                                         \
    wg_barrier(); }

#define GEMM256_CORE()                                                            \
  extern __shared__ __align__(16) u16 lds[];                                      \
  const int t = threadIdx.x;                                                      \
  const int lane = t & 63, w = t >> 6;                                            \
  const int waveM = w >> 2, waveN = w & 3;                                        \
  const int quad = lane >> 4, l16 = lane & 15;                                    \
  const int sR = lane & 15, sC = lane >> 4;                                       \
  u16* AL = lds;                                                                  \
  u16* BL = lds + 32768;                                                          \
  v4f acc[8][4];                                                                  \
  _Pragma("unroll") for (int i = 0; i < 8; i++)                                   \
    _Pragma("unroll") for (int j = 0; j < 4; j++)                                 \
      acc[i][j] = (v4f){0.f, 0.f, 0.f, 0.f};                                      \
  const u16* Ag0 = A + (size_t)(m0 + w * 32 + sR) * DIM + sC * 8;                 \
  const u16* Ag1 = A + (size_t)(m0 + w * 32 + 16 + sR) * DIM + sC * 8;            \
  const u16* Bg0 = Bt + (size_t)(n0 + w * 32 + sR) * DIM + sC * 8;                \
  const u16* Bg1 = Bt + (size_t)(n0 + w * 32 + 16 + sR) * DIM + sC * 8;           \
  u16* Aw0 = AL + (w * 2 + 0) * 512;                                              \
  u16* Aw1 = AL + (w * 2 + 1) * 512;                                              \
  u16* Bw0 = BL + (w * 2 + 0) * 512;                                              \
  u16* Bw1 = BL + (w * 2 + 1) * 512;                                              \
  const int aRd = waveM * 4096 + quad * 128 + l16 * 8;                            \
  const int bRd = waveN * 2048 + quad * 128 + l16 * 8;                            \
  ST_A(0, 0) ST_B(0, 0) ST_A(0, 1) ST_B(0, 1) ST_A(1, 0) ST_B(1, 0)              \
  __builtin_amdgcn_s_waitcnt(WAITCNT_VM4);                                        \
  wg_barrier();                                                                   \
  _Pragma("unroll 2") for (int kt = 0; kt < NKT - 2; kt++) {                      \
    PH(kt, 0, 0, ST_A(kt + 1, 1), )                                               \
    PH(kt, 0, 1, ST_B(kt + 1, 1), )                                               \
    PH(kt, 1, 0, ST_A(kt + 2, 0), )                                               \
    PH(kt, 1, 1, ST_B(kt + 2, 0), __builtin_amdgcn_s_waitcnt(WAITCNT_VM4);)       \
  }                                                                               \
  PH(NKT - 2, 0, 0, ST_A(NKT - 1, 1), )                                           \
  PH(NKT - 2, 0, 1, ST_B(NKT - 1, 1), )                                           \
  PH(NKT - 2, 1, 0, , )                                                           \
  PH(NKT - 2, 1, 1, , __builtin_amdgcn_s_waitcnt(WAITCNT_VM0);)                   \
  PH(NKT - 1, 0, 0, , )                                                           \
  PH(NKT - 1, 0, 1, , )                                                           \
  PH(NKT - 1, 1, 0, , )                                                           \
  PH(NKT - 1, 1, 1, , )

// ---------------- fused QKV GEMM; z=0 -> Q (pre-scaled), z=1 -> K, z=2 -> V transposed ----------------
// 1-D grid of 384 blocks; bijective XCD chunk swizzle (nwg%8==0): each XCD gets
// 48 consecutive (z, m-slab) blocks for L2 reuse of A-rows + one W matrix.
__global__ __launch_bounds__(512, 2) void gemm_qkv(const u16* __restrict__ A, const u16* __restrict__ Wt,
                                                   u16* __restrict__ Qb, u16* __restrict__ Kb,
                                                   u16* __restrict__ Vtg) {
  const int bid = blockIdx.x;
  const int swz = (bid & 7) * 48 + (bid >> 3);
  const int z = swz >> 7;            // 3 x 128 blocks
  const int rem = swz & 127;
  const int m0 = (rem >> 2) * 256;   // 32 m-tiles
  const int n0 = (rem & 3) * 256;    // 4 n-tiles
  const u16* Bt = Wt + (size_t)z * DIM * DIM;
  GEMM256_CORE()
  if (z == 2) {
    // write V transposed: Vtg[((b*NH+h)*HD+d)*SEQ + s]
    #pragma unroll
    for (int mi = 0; mi < 8; mi++) {
      #pragma unroll
      for (int ni = 0; ni < 4; ni++) {
        int gm0 = m0 + waveM * 128 + mi * 16 + quad * 4;
        int gn = n0 + waveN * 64 + ni * 16 + l16;
        int b = gm0 >> 11, s0 = gm0 & (SEQ - 1), hh = gn >> 6, d = gn & (HD - 1);
        u16x4 o;
        #pragma unroll
        for (int r = 0; r < 4; r++) o[r] = f2bf(acc[mi][ni][r]);
        *(u16x4*)(Vtg + ((size_t)(b * NH + hh) * HD + d) * SEQ + s0) = o;
      }
    }
  } else {
    u16* C = (z == 0) ? Qb : Kb;
    #pragma unroll
    for (int mi = 0; mi < 8; mi++) {
      #pragma unroll
      for (int ni = 0; ni < 4; ni++) {
        int gn = n0 + waveN * 64 + ni * 16 + l16;
        #pragma unroll
        for (int r = 0; r < 4; r++) {
          int gm = m0 + waveM * 128 + mi * 16 + quad * 4 + r;
          C[(size_t)gm * DIM + gn] = f2bf(acc[mi][ni][r]);
        }
      }
    }
  }
}

// ---------------- projection GEMM: out = ctx * Wo^T + bias (fp32 out) ----------------
__global__ __launch_bounds__(512, 2) void gemm_proj(const u16* __restrict__ A, const u16* __restrict__ Bt,
                                                    float* __restrict__ Cf, const float* __restrict__ bias) {
  const int bid = blockIdx.x;
  const int swz = (bid & 7) * 16 + (bid >> 3);  // 128 blocks, bijective
  const int m0 = (swz >> 2) * 256;
  const int n0 = (swz & 3) * 256;
  GEMM256_CORE()
  #pragma unroll
  for (int ni = 0; ni < 4; ni++) {
    int gn = n0 + waveN * 64 + ni * 16 + l16;
    float bv = bias[gn];
    #pragma unroll
    for (int mi = 0; mi < 8; mi++) {
      #pragma unroll
      for (int r = 0; r < 4; r++) {
        int gm = m0 + waveM * 128 + mi * 16 + quad * 4 + r;
        Cf[(size_t)gm * DIM + gn] = acc[mi][ni][r] + bv;
      }
    }
  }
}

// ---------------- MFMA flash attention (causal), transposed scores (R4 known-good) ----------------
// S^T = K*Q^T (K rows permuted so P^T registers are directly the PV B-fragment).
// Softmax over kv: 16 in-register values + 2 shfl_xor. O^T = Vt*P^T in C-layout.
// Causal balance: block pair {px, 15-px} -> 34 KV-tiles each. Grid (NH, px, BSZ).
__global__ __launch_bounds__(256, 3) void flash_attn_mfma(const u16* __restrict__ Qb,
                                                          const u16* __restrict__ Kb,
                                                          const u16* __restrict__ Vtg,
                                                          u16* __restrict__ Ob) {
  const int h = blockIdx.x, px = blockIdx.y, bb = blockIdx.z;
  const int t = threadIdx.x;
  const int lane = t & 63, w = t >> 6;
  const int quad = lane >> 4, l16 = lane & 15;

  __shared__ u16 QPs[QT * PAD];  // Q staging, then O^T epilogue bounce
  __shared__ u16 Ks[KT * PAD];   // K tile, rows permuted by pi^-1
  __shared__ u16 Vs[HD * PAD];   // V tile, [d][kv]

  const size_t qkbase = (size_t)bb * SEQ * DIM + h * HD;
  const size_t vbase = ((size_t)bb * NH + h) * (size_t)HD * SEQ;

  const int vrow = t >> 2, scol = (t & 3) * 16;
  const int krow = ((vrow >> 5) + 2 * ((vrow >> 2) & 1)) * 16 + ((vrow >> 3) & 3) * 4 + (vrow & 3);

  for (int pass = 0; pass < 2; pass++) {
    const int qi = (pass == 0) ? px : (SEQ / QT - 1 - px);
    const int q0 = qi * QT;
    const int wq = q0 + w * 32;
    const int ntiles = 2 * qi + 2;

    __syncthreads();  // QPs free (previous pass epilogue complete)

    // stage Q (pure copy; scale folded into Wq)
    {
      const int r = t >> 1, c0 = (t & 1) * 32;
      const u16* src = Qb + qkbase + (size_t)(q0 + r) * DIM + c0;
      #pragma unroll
      for (int ch = 0; ch < 4; ch++)
        *(u16x8*)(QPs + r * PAD + c0 + ch * 8) = *(const u16x8*)(src + ch * 8);
    }
    __syncthreads();

    // Q B-fragments: B[n=q][k=d]
    s8v qf[2][2];
    #pragma unroll
    for (int ni = 0; ni < 2; ni++)
      #pragma unroll
      for (int kc = 0; kc < 2; kc++)
        qf[ni][kc] = *(const s8v*)(QPs + (w * 32 + ni * 16 + l16) * PAD + kc * 32 + quad * 8);

    // preload KV tile 0 into registers
    u16x8 kr0, kr1, vr0, vr1;
    {
      const u16* kp = Kb + qkbase + (size_t)vrow * DIM + scol;
      kr0 = *(const u16x8*)kp; kr1 = *(const u16x8*)(kp + 8);
      const u16* vp = Vtg + vbase + (size_t)vrow * SEQ + scol;
      vr0 = *(const u16x8*)vp; vr1 = *(const u16x8*)(vp + 8);
    }

    float mrun[2] = {-1e30f, -1e30f}, lrun[2] = {0.f, 0.f};
    v4f O[4][2];
    #pragma unroll
    for (int di = 0; di < 4; di++)
      #pragma unroll
      for (int ni = 0; ni < 2; ni++) O[di][ni] = (v4f){0.f, 0.f, 0.f, 0.f};

    for (int it = 0; it < ntiles; ++it) {
      const int kv0 = it * KT;
      __syncthreads();
      *(u16x8*)(Ks + krow * PAD + scol) = kr0;
      *(u16x8*)(Ks + krow * PAD + scol + 8) = kr1;
      *(u16x8*)(Vs + vrow * PAD + scol) = vr0;
      *(u16x8*)(Vs + vrow * PAD + scol + 8) = vr1;
      __syncthreads();
      if (it + 1 < ntiles) {  // prefetch next tile (consumed after next barrier)
        const int nkv = kv0 + KT;
        const u16* kp = Kb + qkbase + (size_t)(nkv + vrow) * DIM + scol;
        kr0 = *(const u16x8*)kp; kr1 = *(const u16x8*)(kp + 8);
        const u16* vp = Vtg + vbase + (size_t)vrow * SEQ + nkv + scol;
        vr0 = *(const u16x8*)vp; vr1 = *(const u16x8*)(vp + 8);
      }
      if (kv0 > wq + 31) continue;  // tile fully masked for this wave

      // ---- S^T = K*Q^T : sc[mi][ni], rows kv (permuted), cols q ----
      v4f sc[4][2];
      #pragma unroll
      for (int mi = 0; mi < 4; mi++)
        #pragma unroll
        for (int ni = 0; ni < 2; ni++) sc[mi][ni] = (v4f){0.f, 0.f, 0.f, 0.f};
      #pragma unroll
      for (int kc = 0; kc < 2; kc++) {
        #pragma unroll
        for (int mi = 0; mi < 4; mi++) {
          s8v kf = *(const s8v*)(Ks + (mi * 16 + l16) * PAD + kc * 32 + quad * 8);
          sc[mi][0] = __builtin_amdgcn_mfma_f32_16x16x32_bf16(kf, qf[0][kc], sc[mi][0], 0, 0, 0);
          sc[mi][1] = __builtin_amdgcn_mfma_f32_16x16x32_bf16(kf, qf[1][kc], sc[mi][1], 0, 0, 0);
        }
      }

      // ---- causal mask: kv_g = kv0 + (mi&1)*32 + quad*8 + (mi>>1)*4 + r ----
      if (kv0 + KT > wq) {
        #pragma unroll
        for (int mi = 0; mi < 4; mi++) {
          const int kvb = kv0 + (mi & 1) * 32 + quad * 8 + (mi >> 1) * 4;
          #pragma unroll
          for (int ni = 0; ni < 2; ni++) {
            const int qg = wq + ni * 16 + l16;
            #pragma unroll
            for (int r = 0; r < 4; r++)
              if (kvb + r > qg) sc[mi][ni][r] = -1e30f;
          }
        }
      }

      // ---- online softmax: per lane 16 kv values, 2 shuffles per reduce ----
      float alpha[2];
      #pragma unroll
      for (int ni = 0; ni < 2; ni++) {
        float mx = -1e30f;
        #pragma unroll
        for (int mi = 0; mi < 4; mi++)
          #pragma unroll
          for (int r = 0; r < 4; r++) mx = fmaxf(mx, sc[mi][ni][r]);
        mx = fmaxf(mx, __shfl_xor(mx, 16, 64));
        mx = fmaxf(mx, __shfl_xor(mx, 32, 64));
        const float mnew = fmaxf(mrun[ni], mx);
        alpha[ni] = fast_exp2(mrun[ni] - mnew);
        mrun[ni] = mnew;
        float rsum = 0.f;
        #pragma unroll
        for (int mi = 0; mi < 4; mi++)
          #pragma unroll
          for (int r = 0; r < 4; r++) {
            float p = fast_exp2(sc[mi][ni][r] - mnew);
            sc[mi][ni][r] = p;
            rsum += p;
          }
        rsum += __shfl_xor(rsum, 16, 64);
        rsum += __shfl_xor(rsum, 32, 64);
        lrun[ni] = lrun[ni] * alpha[ni] + rsum;
      }
      #pragma unroll
      for (int di = 0; di < 4; di++)
        #pragma unroll
        for (int ni = 0; ni < 2; ni++)
          #pragma unroll
          for (int r = 0; r < 4; r++) O[di][ni][r] *= alpha[ni];

      // ---- pack P^T as PV B-frag: pf[ni][kc][j] = P[q][kv=kc*32+quad*8+j] ----
      s8v pf[2][2];
      #pragma unroll
      for (int ni = 0; ni < 2; ni++)
        #pragma unroll
        for (int kc = 0; kc < 2; kc++)
          #pragma unroll
          for (int j = 0; j < 8; j++)
            pf[ni][kc][j] = (short)f2bf(sc[kc + 2 * (j >> 2)][ni][j & 3]);

      // ---- PV: O^T[d][q] += Vt * P^T ----
      #pragma unroll
      for (int kc = 0; kc < 2; kc++) {
        #pragma unroll
        for (int di = 0; di < 4; di++) {
          s8v vf = *(const s8v*)(Vs + (di * 16 + l16) * PAD + kc * 32 + quad * 8);
          O[di][0] = __builtin_amdgcn_mfma_f32_16x16x32_bf16(vf, pf[0][kc], O[di][0], 0, 0, 0);
          O[di][1] = __builtin_amdgcn_mfma_f32_16x16x32_bf16(vf, pf[1][kc], O[di][1], 0, 0, 0);
        }
      }
    }

    // ---- epilogue: normalize, transpose via LDS (wave-private rows), coalesced write ----
    const float inv0 = 1.f / lrun[0], inv1 = 1.f / lrun[1];
    #pragma unroll
    for (int di = 0; di < 4; di++)
      #pragma unroll
      for (int ni = 0; ni < 2; ni++) {
        const float inv = ni ? inv1 : inv0;
        #pragma unroll
        for (int r = 0; r < 4; r++)
          QPs[(w * 32 + ni * 16 + l16) * PAD + di * 16 + quad * 4 + r] = f2bf(O[di][ni][r] * inv);
      }
    __syncthreads();
    {
      const int r = t >> 1, c0 = (t & 1) * 32;
      u16* dst = Ob + qkbase + (size_t)(q0 + r) * DIM + c0;
      #pragma unroll
      for (int ch = 0; ch < 4; ch++)
        *(u16x8*)(dst + ch * 8) = *(const u16x8*)(QPs + r * PAD + c0 + ch * 8);
    }
  }
}

// ---------------- launch ----------------
extern "C" void kernel_launch(void* const* d_in, const int* in_sizes, int n_in,
                              void* d_out, int out_size, void* d_ws, size_t ws_size,
                              hipStream_t stream) {
  (void)in_sizes; (void)n_in; (void)out_size; (void)ws_size;
  const float* x  = (const float*)d_in[0];
  const float* Wq = (const float*)d_in[1];
  const float* Wk = (const float*)d_in[2];
  const float* Wv = (const float*)d_in[3];
  const float* Wo = (const float*)d_in[4];
  const float* bo = (const float*)d_in[5];
  float* out = (float*)d_out;

  // raise the dynamic-LDS cap once (128 KiB per GEMM block; gfx950 has 160)
  static bool lds_attr_done = false;
  if (!lds_attr_done) {
    hipFuncSetAttribute(reinterpret_cast<const void*>(gemm_qkv),
                        hipFuncAttributeMaxDynamicSharedMemorySize, 131072);
    hipFuncSetAttribute(reinterpret_cast<const void*>(gemm_proj),
                        hipFuncAttributeMaxDynamicSharedMemorySize, 131072);
    lds_attr_done = true;
  }

  char* ws = (char*)d_ws;
  const size_t MB = 1024ull * 1024ull;
  u16* Xb  = (u16*)(ws);             // 16 MB: x bf16 [8192][1024]
  u16* Wt  = (u16*)(ws + 16 * MB);   //  8 MB: Wq(scaled),Wk,Wv,Wo transposed bf16
  u16* Qb  = (u16*)(ws + 24 * MB);   // 16 MB
  u16* Kb  = (u16*)(ws + 40 * MB);   // 16 MB
  u16* Vtg = (u16*)(ws + 56 * MB);   // 16 MB: V transposed [b][h][d][s]
  u16* Cb  = (u16*)(ws + 72 * MB);   // 16 MB: ctx -> 88 MB total

  const int NTOK = BSZ * SEQ;  // 8192
  const int n4 = NTOK * DIM / 4;
  cast_bf16_kernel<<<(n4 + 255) / 256, 256, 0, stream>>>(x, Xb, n4);
  transpose_cast_kernel<<<dim3(32, 32, 4), 256, 0, stream>>>(Wq, Wk, Wv, Wo, Wt);

  // 3 * (8192/256) * (1024/256) = 384 blocks, 512 threads, 128 KiB dynamic LDS
  gemm_qkv<<<dim3(384), 512, 131072, stream>>>(Xb, Wt, Qb, Kb, Vtg);

  flash_attn_mfma<<<dim3(NH, SEQ / QT / 2, BSZ), 256, 0, stream>>>(Qb, Kb, Vtg, Cb);

  // (8192/256) * (1024/256) = 128 blocks
  gemm_proj<<<dim3(128), 512, 131072, stream>>>(Cb, Wt + 3ull * DIM * DIM, out, bo);
}

// Round 2
// 266.210 us; speedup vs baseline: 1.1397x; 1.0685x over previous
//
#include <hip/hip_runtime.h>

// ---- problem constants ----
#define BSZ 4
#define SEQ 2048
#define DIM 1024
#define NH  16
#define HD  64
#define QT  128   // q rows per block pass (flash)
#define KT  64    // kv rows per tile (flash)
#define PAD 72    // u16 row stride in flash LDS
#define NKT (DIM / 64)  // 16 K-tiles of 64

typedef float v4f __attribute__((ext_vector_type(4)));
typedef short s8v __attribute__((ext_vector_type(8)));
typedef unsigned short u16;
typedef unsigned short u16x8 __attribute__((ext_vector_type(8)));
typedef unsigned short u16x4 __attribute__((ext_vector_type(4)));
typedef unsigned int u32;
typedef unsigned int u32x2 __attribute__((ext_vector_type(2)));
typedef unsigned int u32x4 __attribute__((ext_vector_type(4)));

__device__ __forceinline__ u16 f2bf(float f) {
  u32 u = __builtin_bit_cast(u32, f);
  u32 r = u + 0x7fffu + ((u >> 16) & 1u);  // RNE
  return (u16)(r >> 16);
}
// single v_cvt_pk_bf16_f32 (RNE) — 1 inst for 2 elems
__device__ __forceinline__ u32 cvtpk(float lo, float hi) {
  u32 r; asm("v_cvt_pk_bf16_f32 %0, %1, %2" : "=v"(r) : "v"(lo), "v"(hi)); return r;
}
__device__ __forceinline__ u16 f2bf1(float f) { return (u16)cvtpk(f, f); }
__device__ __forceinline__ float fast_exp2(float x) {
#if __has_builtin(__builtin_amdgcn_exp2f)
  return __builtin_amdgcn_exp2f(x);
#else
  return exp2f(x);
#endif
}
// async global->LDS, 16B per lane; lds ptr must be wave-uniform (HW adds lane*16)
__device__ __forceinline__ void gll16(const u16* g, u16* l) {
  __builtin_amdgcn_global_load_lds((const __attribute__((address_space(1))) void*)g,
                                   (__attribute__((address_space(3))) void*)l, 16, 0, 0);
}
// raw s_barrier: SIInsertWaitcnts does NOT recognize it -> no forced vmcnt(0) drain.
__device__ __forceinline__ void wg_barrier() { asm volatile("s_barrier" ::: "memory"); }
// s_waitcnt imm: vmcnt[3:0] | expcnt<<4 | lgkmcnt<<8 | vmcnt[5:4]<<14
#define WAITCNT_LGKM0 0xC07F  // lgkmcnt(0), vm/exp unconstrained
#define VMW6 __builtin_amdgcn_s_waitcnt(0xF76);
#define VMW0 __builtin_amdgcn_s_waitcnt(0xF70);

// ---------------- cast x (fp32) -> bf16 ----------------
__global__ __launch_bounds__(256) void cast_bf16_kernel(const float* __restrict__ x,
                                                        u16* __restrict__ o, int n4) {
  int i = blockIdx.x * 256 + threadIdx.x;
  if (i >= n4) return;
  v4f v = reinterpret_cast<const v4f*>(x)[i];
  u16x4 r;
  #pragma unroll
  for (int c = 0; c < 4; c++) r[c] = f2bf(v[c]);
  reinterpret_cast<u16x4*>(o)[i] = r;
}

// ---------------- transpose + cast W[k][n] -> Wt[n][k] bf16 ----------------
// z==0 (Wq) folds in 1/sqrt(HD)*log2(e): Q leaves the QKV GEMM pre-scaled.
__global__ __launch_bounds__(256) void transpose_cast_kernel(const float* __restrict__ W0,
                                                             const float* __restrict__ W1,
                                                             const float* __restrict__ W2,
                                                             const float* __restrict__ W3,
                                                             u16* __restrict__ out) {
  const float* W = blockIdx.z == 0 ? W0 : blockIdx.z == 1 ? W1 : blockIdx.z == 2 ? W2 : W3;
  const float scale = (blockIdx.z == 0) ? 0.18033688011112042f : 1.0f;
  u16* T = out + (size_t)blockIdx.z * DIM * DIM;
  __shared__ float tile[32][33];
  int tx = threadIdx.x & 31, ty = threadIdx.x >> 5;
  int bn = blockIdx.x * 32, bk = blockIdx.y * 32;
  #pragma unroll
  for (int r = 0; r < 4; r++) {
    int k = bk + ty + r * 8;
    tile[ty + r * 8][tx] = W[(size_t)k * DIM + bn + tx];
  }
  __syncthreads();
  #pragma unroll
  for (int r = 0; r < 4; r++) {
    int n = bn + ty + r * 8;
    T[(size_t)n * DIM + bk + tx] = f2bf(tile[tx][ty + r * 8] * scale);
  }
}

// ======== 256x128 GEMM core: BK=64, 512 thr = 8 waves 4Mx2N, wave-tile 64x64 ========
// ONE phase per K-tile: [16 ds_read_b128; stage tile t+2 (6 gll16); vmcnt(6);
// barrier; lgkmcnt(0); setprio(1); 32 MFMA; setprio(0); barrier].
// 3-stage LDS (144 KiB): slot(t) = t%3; slot reused at t+3, freed at end of
// phase t (trailing barrier), re-staged at phase t+1 (one-barrier separation),
// consumed at phase t+3 (flight ~1.7 phases >> HBM latency). vmcnt(6) at phase
// p (outstanding = units p+1,p+2 = 12 loads) guarantees unit p+1 landed before
// the trailing barrier releases its readers. Never drains to 0 in the loop.
// LDS unit layout (gll16 lane-linear, conflict-free reads): chunk g = row>>4
// at g*512 u16; within chunk lane(sR,sC) at sC*128+sR*8.
// A: [3][2kc][8192 u16] @ 0 (96 KiB); B: [3][2kc][4096 u16] @ 49152 (48 KiB).

#define ST_TILE(t_, s_)                                                           \
  gll16(Ag0 + (t_) * 64,      AW0 + (s_) * 16384);                                \
  gll16(Ag1 + (t_) * 64,      AW1 + (s_) * 16384);                                \
  gll16(Ag0 + (t_) * 64 + 32, AW0 + (s_) * 16384 + 8192);                         \
  gll16(Ag1 + (t_) * 64 + 32, AW1 + (s_) * 16384 + 8192);                         \
  gll16(Bg0 + (t_) * 64,      BW0 + (s_) * 8192);                                 \
  gll16(Bg0 + (t_) * 64 + 32, BW0 + (s_) * 8192 + 4096);

#define PH(t_, s_, STAGES, VMW)                                                   \
  { const u16* Ab = AL + (s_) * 16384 + aRd;                                      \
    const u16* Bb = BL + (s_) * 8192 + bRd;                                       \
    s8v af[2][4], bf[2][4];                                                       \
    _Pragma("unroll") for (int kc_ = 0; kc_ < 2; kc_++) {                         \
      _Pragma("unroll") for (int i_ = 0; i_ < 4; i_++)                            \
        af[kc_][i_] = *(const s8v*)(Ab + kc_ * 8192 + i_ * 512);                  \
      _Pragma("unroll") for (int j_ = 0; j_ < 4; j_++)                            \
        bf[kc_][j_] = *(const s8v*)(Bb + kc_ * 4096 + j_ * 512);                  \
    }                                                                             \
    STAGES                                                                        \
    VMW                                                                           \
    wg_barrier();                                                                 \
    __builtin_amdgcn_s_waitcnt(WAITCNT_LGKM0);                                    \
    __builtin_amdgcn_s_setprio(1);                                                \
    _Pragma("unroll") for (int kc_ = 0; kc_ < 2; kc_++)                           \
      _Pragma("unroll") for (int i_ = 0; i_ < 4; i_++)                            \
        _Pragma("unroll") for (int j_ = 0; j_ < 4; j_++)                          \
          acc[i_][j_] = __builtin_amdgcn_mfma_f32_16x16x32_bf16(                  \
              af[kc_][i_], bf[kc_][j_], acc[i_][j_], 0, 0, 0);                    \
    __builtin_amdgcn_s_setprio(0);                                                \
    wg_barrier(); }

#define GEMM256x128_CORE()                                                        \
  extern __shared__ __align__(16) u16 lds[];                                      \
  const int t = threadIdx.x;                                                      \
  const int lane = t & 63, w = t >> 6;                                            \
  const int waveM = w >> 1, waveN = w & 1;                                        \
  const int quad = lane >> 4, l16 = lane & 15;                                    \
  const int sR = lane & 15, sC = lane >> 4;                                       \
  u16* AL = lds;                                                                  \
  u16* BL = lds + 49152;                                                          \
  v4f acc[4][4];                                                                  \
  _Pragma("unroll") for (int i = 0; i < 4; i++)                                   \
    _Pragma("unroll") for (int j = 0; j < 4; j++)                                 \
      acc[i][j] = (v4f){0.f, 0.f, 0.f, 0.f};                                      \
  const u16* Ag0 = A + (size_t)(m0 + w * 32 + sR) * DIM + sC * 8;                 \
  const u16* Ag1 = Ag0 + 16 * DIM;                                                \
  const u16* Bg0 = Bt + (size_t)(n0 + w * 16 + sR) * DIM + sC * 8;                \
  u16* AW0 = AL + w * 1024;                                                       \
  u16* AW1 = AL + w * 1024 + 512;                                                 \
  u16* BW0 = BL + w * 512;                                                        \
  const int aRd = waveM * 2048 + quad * 128 + l16 * 8;                            \
  const int bRd = waveN * 2048 + quad * 128 + l16 * 8;                            \
  ST_TILE(0, 0) ST_TILE(1, 1)                                                     \
  VMW6                                                                            \
  wg_barrier();                                                                   \
  _Pragma("unroll") for (int t3 = 0; t3 < 12; t3 += 3) {                          \
    PH(t3 + 0, 0, ST_TILE(t3 + 2, 2), VMW6)                                       \
    PH(t3 + 1, 1, ST_TILE(t3 + 3, 0), VMW6)                                       \
    PH(t3 + 2, 2, ST_TILE(t3 + 4, 1), VMW6)                                       \
  }                                                                               \
  PH(12, 0, ST_TILE(14, 2), VMW6)                                                 \
  PH(13, 1, ST_TILE(15, 0), VMW6)                                                 \
  PH(14, 2, , VMW0)                                                               \
  PH(15, 0, , )

// ---------------- fused QKV GEMM; z=0 -> Q (pre-scaled), z=1 -> K, z=2 -> V^T ----------------
// 768 blocks = exactly 3 full CU epochs. Bijective XCD chunk swizzle (768%8==0):
// each XCD owns 96 consecutive (z, m-slab, n) tiles for L2 A-row + W reuse.
__global__ __launch_bounds__(512, 2) void gemm_qkv(const u16* __restrict__ A, const u16* __restrict__ Wt,
                                                   u16* __restrict__ Qb, u16* __restrict__ Kb,
                                                   u16* __restrict__ Vtg) {
  const int bid = blockIdx.x;
  const int swz = (bid & 7) * 96 + (bid >> 3);
  const int z = swz >> 8;            // 3 x 256 blocks
  const int rem = swz & 255;
  const int m0 = (rem >> 3) * 256;   // 32 m-tiles
  const int n0 = (rem & 7) * 128;    // 8 n-tiles
  const u16* Bt = Wt + (size_t)z * DIM * DIM;
  GEMM256x128_CORE()
  if (z == 2) {
    // write V transposed: Vtg[((b*NH+h)*HD+d)*SEQ + s]
    #pragma unroll
    for (int mi = 0; mi < 4; mi++) {
      #pragma unroll
      for (int ni = 0; ni < 4; ni++) {
        int gm0 = m0 + waveM * 64 + mi * 16 + quad * 4;
        int gn = n0 + waveN * 64 + ni * 16 + l16;
        int b = gm0 >> 11, s0 = gm0 & (SEQ - 1), hh = gn >> 6, d = gn & (HD - 1);
        u32x2 pw;
        pw[0] = cvtpk(acc[mi][ni][0], acc[mi][ni][1]);
        pw[1] = cvtpk(acc[mi][ni][2], acc[mi][ni][3]);
        *(u16x4*)(Vtg + ((size_t)(b * NH + hh) * HD + d) * SEQ + s0) =
            __builtin_bit_cast(u16x4, pw);
      }
    }
  } else {
    u16* C = (z == 0) ? Qb : Kb;
    #pragma unroll
    for (int mi = 0; mi < 4; mi++) {
      #pragma unroll
      for (int ni = 0; ni < 4; ni++) {
        int gn = n0 + waveN * 64 + ni * 16 + l16;
        #pragma unroll
        for (int r = 0; r < 4; r++) {
          int gm = m0 + waveM * 64 + mi * 16 + quad * 4 + r;
          C[(size_t)gm * DIM + gn] = f2bf1(acc[mi][ni][r]);
        }
      }
    }
  }
}

// ---------------- projection GEMM: out = ctx * Wo^T + bias (fp32 out) ----------------
// 256 blocks = exactly 1 CU epoch.
__global__ __launch_bounds__(512, 2) void gemm_proj(const u16* __restrict__ A, const u16* __restrict__ Bt,
                                                    float* __restrict__ Cf, const float* __restrict__ bias) {
  const int bid = blockIdx.x;
  const int swz = (bid & 7) * 32 + (bid >> 3);  // bijective
  const int m0 = (swz >> 3) * 256;
  const int n0 = (swz & 7) * 128;
  GEMM256x128_CORE()
  #pragma unroll
  for (int ni = 0; ni < 4; ni++) {
    int gn = n0 + waveN * 64 + ni * 16 + l16;
    float bv = bias[gn];
    #pragma unroll
    for (int mi = 0; mi < 4; mi++) {
      #pragma unroll
      for (int r = 0; r < 4; r++) {
        int gm = m0 + waveM * 64 + mi * 16 + quad * 4 + r;
        Cf[(size_t)gm * DIM + gn] = acc[mi][ni][r] + bv;
      }
    }
  }
}

// ---------------- MFMA flash attention (causal), transposed scores ----------------
// S^T = K*Q^T (K rows permuted so P^T registers are directly the PV B-fragment).
// Softmax over kv: 16 in-register values + 2 shfl_xor. O^T = Vt*P^T in C-layout.
// Causal balance: block pair {px, 15-px} -> 34 KV-tiles each. Grid (NH, px, BSZ).
// VALU cuts this round: v_cvt_pk_bf16_f32 P-pack (1 inst / 2 elems) and
// defer-max (T13, THR=8 in exp2 domain): skip the O-rescale when no column's
// max grew by >8; no fully-masked columns exist (tile-skip guarantees kv0<=q).
__global__ __launch_bounds__(256, 3) void flash_attn_mfma(const u16* __restrict__ Qb,
                                                          const u16* __restrict__ Kb,
                                                          const u16* __restrict__ Vtg,
                                                          u16* __restrict__ Ob) {
  const int h = blockIdx.x, px = blockIdx.y, bb = blockIdx.z;
  const int t = threadIdx.x;
  const int lane = t & 63, w = t >> 6;
  const int quad = lane >> 4, l16 = lane & 15;

  __shared__ u16 QPs[QT * PAD];  // Q staging, then O^T epilogue bounce
  __shared__ u16 Ks[KT * PAD];   // K tile, rows permuted by pi^-1
  __shared__ u16 Vs[HD * PAD];   // V tile, [d][kv]

  const size_t qkbase = (size_t)bb * SEQ * DIM + h * HD;
  const size_t vbase = ((size_t)bb * NH + h) * (size_t)HD * SEQ;

  const int vrow = t >> 2, scol = (t & 3) * 16;
  const int krow = ((vrow >> 5) + 2 * ((vrow >> 2) & 1)) * 16 + ((vrow >> 3) & 3) * 4 + (vrow & 3);

  for (int pass = 0; pass < 2; pass++) {
    const int qi = (pass == 0) ? px : (SEQ / QT - 1 - px);
    const int q0 = qi * QT;
    const int wq = q0 + w * 32;
    const int ntiles = 2 * qi + 2;

    __syncthreads();  // QPs free (previous pass epilogue complete)

    // stage Q (pure copy; scale folded into Wq)
    {
      const int r = t >> 1, c0 = (t & 1) * 32;
      const u16* src = Qb + qkbase + (size_t)(q0 + r) * DIM + c0;
      #pragma unroll
      for (int ch = 0; ch < 4; ch++)
        *(u16x8*)(QPs + r * PAD + c0 + ch * 8) = *(const u16x8*)(src + ch * 8);
    }
    __syncthreads();

    // Q B-fragments: B[n=q][k=d]
    s8v qf[2][2];
    #pragma unroll
    for (int ni = 0; ni < 2; ni++)
      #pragma unroll
      for (int kc = 0; kc < 2; kc++)
        qf[ni][kc] = *(const s8v*)(QPs + (w * 32 + ni * 16 + l16) * PAD + kc * 32 + quad * 8);

    // preload KV tile 0 into registers
    u16x8 kr0, kr1, vr0, vr1;
    {
      const u16* kp = Kb + qkbase + (size_t)vrow * DIM + scol;
      kr0 = *(const u16x8*)kp; kr1 = *(const u16x8*)(kp + 8);
      const u16* vp = Vtg + vbase + (size_t)vrow * SEQ + scol;
      vr0 = *(const u16x8*)vp; vr1 = *(const u16x8*)(vp + 8);
    }

    float mrun[2] = {-1e30f, -1e30f}, lrun[2] = {0.f, 0.f};
    v4f O[4][2];
    #pragma unroll
    for (int di = 0; di < 4; di++)
      #pragma unroll
      for (int ni = 0; ni < 2; ni++) O[di][ni] = (v4f){0.f, 0.f, 0.f, 0.f};

    for (int it = 0; it < ntiles; ++it) {
      const int kv0 = it * KT;
      __syncthreads();
      *(u16x8*)(Ks + krow * PAD + scol) = kr0;
      *(u16x8*)(Ks + krow * PAD + scol + 8) = kr1;
      *(u16x8*)(Vs + vrow * PAD + scol) = vr0;
      *(u16x8*)(Vs + vrow * PAD + scol + 8) = vr1;
      __syncthreads();
      if (it + 1 < ntiles) {  // prefetch next tile (consumed after next barrier)
        const int nkv = kv0 + KT;
        const u16* kp = Kb + qkbase + (size_t)(nkv + vrow) * DIM + scol;
        kr0 = *(const u16x8*)kp; kr1 = *(const u16x8*)(kp + 8);
        const u16* vp = Vtg + vbase + (size_t)vrow * SEQ + nkv + scol;
        vr0 = *(const u16x8*)vp; vr1 = *(const u16x8*)(vp + 8);
      }
      if (kv0 > wq + 31) continue;  // tile fully masked for this wave

      // ---- S^T = K*Q^T : sc[mi][ni], rows kv (permuted), cols q ----
      v4f sc[4][2];
      #pragma unroll
      for (int mi = 0; mi < 4; mi++)
        #pragma unroll
        for (int ni = 0; ni < 2; ni++) sc[mi][ni] = (v4f){0.f, 0.f, 0.f, 0.f};
      #pragma unroll
      for (int kc = 0; kc < 2; kc++) {
        #pragma unroll
        for (int mi = 0; mi < 4; mi++) {
          s8v kf = *(const s8v*)(Ks + (mi * 16 + l16) * PAD + kc * 32 + quad * 8);
          sc[mi][0] = __builtin_amdgcn_mfma_f32_16x16x32_bf16(kf, qf[0][kc], sc[mi][0], 0, 0, 0);
          sc[mi][1] = __builtin_amdgcn_mfma_f32_16x16x32_bf16(kf, qf[1][kc], sc[mi][1], 0, 0, 0);
        }
      }

      // ---- causal mask: kv_g = kv0 + (mi&1)*32 + quad*8 + (mi>>1)*4 + r ----
      if (kv0 + KT > wq) {
        #pragma unroll
        for (int mi = 0; mi < 4; mi++) {
          const int kvb = kv0 + (mi & 1) * 32 + quad * 8 + (mi >> 1) * 4;
          #pragma unroll
          for (int ni = 0; ni < 2; ni++) {
            const int qg = wq + ni * 16 + l16;
            #pragma unroll
            for (int r = 0; r < 4; r++)
              if (kvb + r > qg) sc[mi][ni][r] = -1e30f;
          }
        }
      }

      // ---- online softmax with defer-max (THR=8, exp2 domain) ----
      float mx[2];
      #pragma unroll
      for (int ni = 0; ni < 2; ni++) {
        float m = -1e30f;
        #pragma unroll
        for (int mi = 0; mi < 4; mi++)
          #pragma unroll
          for (int r = 0; r < 4; r++) m = fmaxf(m, sc[mi][ni][r]);
        m = fmaxf(m, __shfl_xor(m, 16, 64));
        m = fmaxf(m, __shfl_xor(m, 32, 64));
        mx[ni] = m;
      }
      const bool defer = __all((mx[0] <= mrun[0] + 8.f) && (mx[1] <= mrun[1] + 8.f));
      if (!defer) {
        float alpha[2];
        #pragma unroll
        for (int ni = 0; ni < 2; ni++) {
          const float mnew = fmaxf(mrun[ni], mx[ni]);
          alpha[ni] = fast_exp2(mrun[ni] - mnew);
          mrun[ni] = mnew;
          lrun[ni] *= alpha[ni];
        }
        #pragma unroll
        for (int di = 0; di < 4; di++)
          #pragma unroll
          for (int ni = 0; ni < 2; ni++)
            #pragma unroll
            for (int r = 0; r < 4; r++) O[di][ni][r] *= alpha[ni];
      }
      #pragma unroll
      for (int ni = 0; ni < 2; ni++) {
        float rsum = 0.f;
        #pragma unroll
        for (int mi = 0; mi < 4; mi++)
          #pragma unroll
          for (int r = 0; r < 4; r++) {
            float p = fast_exp2(sc[mi][ni][r] - mrun[ni]);
            sc[mi][ni][r] = p;
            rsum += p;
          }
        rsum += __shfl_xor(rsum, 16, 64);
        rsum += __shfl_xor(rsum, 32, 64);
        lrun[ni] += rsum;
      }

      // ---- pack P^T as PV B-frag via v_cvt_pk_bf16_f32 ----
      // pf[ni][kc] lanes j: j=0..3 -> sc[kc][ni][j], j=4..7 -> sc[kc+2][ni][j-4]
      s8v pf[2][2];
      #pragma unroll
      for (int ni = 0; ni < 2; ni++)
        #pragma unroll
        for (int kc = 0; kc < 2; kc++) {
          u32x4 wds;
          wds[0] = cvtpk(sc[kc][ni][0], sc[kc][ni][1]);
          wds[1] = cvtpk(sc[kc][ni][2], sc[kc][ni][3]);
          wds[2] = cvtpk(sc[kc + 2][ni][0], sc[kc + 2][ni][1]);
          wds[3] = cvtpk(sc[kc + 2][ni][2], sc[kc + 2][ni][3]);
          pf[ni][kc] = __builtin_bit_cast(s8v, wds);
        }

      // ---- PV: O^T[d][q] += Vt * P^T ----
      #pragma unroll
      for (int kc = 0; kc < 2; kc++) {
        #pragma unroll
        for (int di = 0; di < 4; di++) {
          s8v vf = *(const s8v*)(Vs + (di * 16 + l16) * PAD + kc * 32 + quad * 8);
          O[di][0] = __builtin_amdgcn_mfma_f32_16x16x32_bf16(vf, pf[0][kc], O[di][0], 0, 0, 0);
          O[di][1] = __builtin_amdgcn_mfma_f32_16x16x32_bf16(vf, pf[1][kc], O[di][1], 0, 0, 0);
        }
      }
    }

    // ---- epilogue: normalize, transpose via LDS (wave-private rows), coalesced write ----
    const float inv0 = 1.f / lrun[0], inv1 = 1.f / lrun[1];
    #pragma unroll
    for (int di = 0; di < 4; di++)
      #pragma unroll
      for (int ni = 0; ni < 2; ni++) {
        const float inv = ni ? inv1 : inv0;
        #pragma unroll
        for (int r = 0; r < 4; r++)
          QPs[(w * 32 + ni * 16 + l16) * PAD + di * 16 + quad * 4 + r] = f2bf1(O[di][ni][r] * inv);
      }
    __syncthreads();
    {
      const int r = t >> 1, c0 = (t & 1) * 32;
      u16* dst = Ob + qkbase + (size_t)(q0 + r) * DIM + c0;
      #pragma unroll
      for (int ch = 0; ch < 4; ch++)
        *(u16x8*)(dst + ch * 8) = *(const u16x8*)(QPs + r * PAD + c0 + ch * 8);
    }
  }
}

// ---------------- launch ----------------
extern "C" void kernel_launch(void* const* d_in, const int* in_sizes, int n_in,
                              void* d_out, int out_size, void* d_ws, size_t ws_size,
                              hipStream_t stream) {
  (void)in_sizes; (void)n_in; (void)out_size; (void)ws_size;
  const float* x  = (const float*)d_in[0];
  const float* Wq = (const float*)d_in[1];
  const float* Wk = (const float*)d_in[2];
  const float* Wv = (const float*)d_in[3];
  const float* Wo = (const float*)d_in[4];
  const float* bo = (const float*)d_in[5];
  float* out = (float*)d_out;

  // raise the dynamic-LDS cap once (144 KiB per GEMM block; gfx950 has 160)
  static bool lds_attr_done = false;
  if (!lds_attr_done) {
    hipFuncSetAttribute(reinterpret_cast<const void*>(gemm_qkv),
                        hipFuncAttributeMaxDynamicSharedMemorySize, 147456);
    hipFuncSetAttribute(reinterpret_cast<const void*>(gemm_proj),
                        hipFuncAttributeMaxDynamicSharedMemorySize, 147456);
    lds_attr_done = true;
  }

  char* ws = (char*)d_ws;
  const size_t MB = 1024ull * 1024ull;
  u16* Xb  = (u16*)(ws);             // 16 MB: x bf16 [8192][1024]
  u16* Wt  = (u16*)(ws + 16 * MB);   //  8 MB: Wq(scaled),Wk,Wv,Wo transposed bf16
  u16* Qb  = (u16*)(ws + 24 * MB);   // 16 MB
  u16* Kb  = (u16*)(ws + 40 * MB);   // 16 MB
  u16* Vtg = (u16*)(ws + 56 * MB);   // 16 MB: V transposed [b][h][d][s]
  u16* Cb  = (u16*)(ws + 72 * MB);   // 16 MB: ctx -> 88 MB total

  const int NTOK = BSZ * SEQ;  // 8192
  const int n4 = NTOK * DIM / 4;
  cast_bf16_kernel<<<(n4 + 255) / 256, 256, 0, stream>>>(x, Xb, n4);
  transpose_cast_kernel<<<dim3(32, 32, 4), 256, 0, stream>>>(Wq, Wk, Wv, Wo, Wt);

  // 3 * (8192/256) * (1024/128) = 768 blocks = 3 clean CU epochs
  gemm_qkv<<<dim3(768), 512, 147456, stream>>>(Xb, Wt, Qb, Kb, Vtg);

  flash_attn_mfma<<<dim3(NH, SEQ / QT / 2, BSZ), 256, 0, stream>>>(Qb, Kb, Vtg, Cb);

  // (8192/256) * (1024/128) = 256 blocks = 1 clean CU epoch
  gemm_proj<<<dim3(256), 512, 147456, stream>>>(Cb, Wt + 3ull * DIM * DIM, out, bo);
}